// Round 11
// baseline (285.171 us; speedup 1.0000x reference)
//
#include <hip/hip_runtime.h>
#include <math.h>

// UNISURF renderer, MI355X — single-kernel slim-MFMA, 3-wave edition.
// R10 -> R11: target the VGPR=188 -> <=168 boundary (3 waves/SIMD = 12
// waves/CU, matching LDS's 3 blocks/CU). Two edits: (a) A-build loads u/v in
// two float4 halves (8 live regs not 16); (b) amdgpu_num_vgpr(168) hard cap
// (NOT launch_bounds(256,N>=2): that targets 256/N and mega-spills; here we
// shave 20 regs below natural use, expecting cold-value spills only —
// WRITE_SIZE is the sentinel).
//
// Verified fragment layout (R5-R10 passed):
//   A: row = lane&15,  k = 4*(lane>>4) + (e&3) + 16*(e>>2)   (e = 0..7)
//   B: col = lane&15,  same k-map
//   C: col = lane&15,  row = 4*(lane>>4) + reg

#define HID 128
#define NEARF 0.8f
#define FARF  1.8f

typedef __attribute__((ext_vector_type(8))) _Float16 half8;
typedef __attribute__((ext_vector_type(4))) float f32x4;

__device__ __forceinline__ float sigmoidf_(float x) { return 1.0f / (1.0f + expf(-x)); }

// One M-quarter (16 sample-rows) of the 128->128->heads MLP on MFMA.
// dq = depth for this lane's A-row (sample row = lane&15 of quarter mq).
// Scatters per-sample results into sred[mq*16 + row] (+64/128/192 if RGB).
template<bool RGB>
__device__ __forceinline__ void eval_q(
    const float* __restrict__ su, const float* __restrict__ sv,
    const _Float16* __restrict__ sW2F,
    const float* __restrict__ sB2, const float* __restrict__ sWo,
    const float* __restrict__ sWc, float* __restrict__ sred,
    int mq, float dq, int lane)
{
    const int g = lane >> 4, nl = lane & 15;
    f32x4 acc[8];
#pragma unroll
    for (int nt = 0; nt < 8; ++nt) acc[nt] = (f32x4){0.f, 0.f, 0.f, 0.f};

#pragma unroll
    for (int kt = 0; kt < 4; ++kt) {
        const float* uk = su + kt * 32 + 4 * g;
        const float* vk = sv + kt * 32 + 4 * g;
        half8 Ah, Al;
#pragma unroll
        for (int eh = 0; eh < 2; ++eh) {          // two e-halves: 8 live u/v regs
            const float4 uq = *reinterpret_cast<const float4*>(uk + 16 * eh);
            const float4 vq = *reinterpret_cast<const float4*>(vk + 16 * eh);
            const float uu[4] = {uq.x, uq.y, uq.z, uq.w};
            const float vv[4] = {vq.x, vq.y, vq.z, vq.w};
#pragma unroll
            for (int e2 = 0; e2 < 4; ++e2) {
                const int e = eh * 4 + e2;
                const float h = fmaxf(fmaf(dq, vv[e2], uu[e2]), 0.f);
                const _Float16 hh = (_Float16)h;
                Ah[e] = hh;
                Al[e] = (_Float16)(h - (float)hh);
            }
        }
#pragma unroll
        for (int nt = 0; nt < 8; ++nt) {
            const int frag = (kt * 8 + nt) * 64 + lane;
            const half8 B = *reinterpret_cast<const half8*>(&sW2F[frag * 8]);
            acc[nt] = __builtin_amdgcn_mfma_f32_16x16x32_f16(Ah, B, acc[nt], 0, 0, 0);
            acc[nt] = __builtin_amdgcn_mfma_f32_16x16x32_f16(Al, B, acc[nt], 0, 0, 0);
        }
    }

    // epilogue: h2 = relu(acc + b2); head partials
    float pl[4], p0[4], p1[4], p2[4];
#pragma unroll
    for (int r = 0; r < 4; ++r) { pl[r] = 0.f; if (RGB) { p0[r] = 0.f; p1[r] = 0.f; p2[r] = 0.f; } }
#pragma unroll
    for (int nt = 0; nt < 8; ++nt) {
        const int j = nt * 16 + nl;
        const float b2l = sB2[j], wol = sWo[j];
        float wc0 = 0.f, wc1 = 0.f, wc2 = 0.f;
        if (RGB) { wc0 = sWc[j * 3 + 0]; wc1 = sWc[j * 3 + 1]; wc2 = sWc[j * 3 + 2]; }
#pragma unroll
        for (int r = 0; r < 4; ++r) {
            const float h2 = fmaxf(acc[nt][r] + b2l, 0.f);
            pl[r] = fmaf(h2, wol, pl[r]);
            if (RGB) {
                p0[r] = fmaf(h2, wc0, p0[r]);
                p1[r] = fmaf(h2, wc1, p1[r]);
                p2[r] = fmaf(h2, wc2, p2[r]);
            }
        }
    }
    // reduce across the 16 lanes of each g-group (j varies across them)
#pragma unroll
    for (int off = 1; off < 16; off <<= 1) {
#pragma unroll
        for (int r = 0; r < 4; ++r) {
            pl[r] += __shfl_xor(pl[r], off);
            if (RGB) {
                p0[r] += __shfl_xor(p0[r], off);
                p1[r] += __shfl_xor(p1[r], off);
                p2[r] += __shfl_xor(p2[r], off);
            }
        }
    }
    if (nl == 0) {
#pragma unroll
        for (int r = 0; r < 4; ++r) {
            const int m = mq * 16 + 4 * g + r;
            sred[m] = pl[r];
            if (RGB) { sred[64 + m] = p0[r]; sred[128 + m] = p1[r]; sred[192 + m] = p2[r]; }
        }
    }
}

extern "C" __global__ void __launch_bounds__(256, 1)
__attribute__((amdgpu_num_vgpr(168)))
unisurf_mfma_kernel(
    const float* __restrict__ raysDir, const float* __restrict__ raysOrg,
    const float* __restrict__ W1, const float* __restrict__ b1,
    const float* __restrict__ W2, const float* __restrict__ b2,
    const float* __restrict__ Wo, const float* __restrict__ bo,
    const float* __restrict__ Wc, const float* __restrict__ bc,
    const int* __restrict__ itp,
    float* __restrict__ outRGB, float* __restrict__ outD, float* __restrict__ outM,
    int nRays)
{
    __shared__ __align__(16) _Float16 sW2F[2048 * 8];   // B-frag fp16 (32KB)
    __shared__ __align__(16) float sU[4][HID];
    __shared__ __align__(16) float sV[4][HID];
    __shared__ __align__(16) float sB2[HID];
    __shared__ __align__(16) float sWoS[HID];
    __shared__ __align__(16) float sWc[HID * 3];
    __shared__ __align__(16) float sRed[4][256];

    const int tid = threadIdx.x;
    // ---- stage W2 into MFMA B-fragment order, fp16 -------------------------
    for (int s = tid; s < 2048; s += 256) {
        const int ln = s & 63, ntg = (s >> 6) & 7, kt = s >> 9;
        const int n = ntg * 16 + (ln & 15), gg = ln >> 4;
        half8 hp;
#pragma unroll
        for (int e = 0; e < 8; ++e) {
            const int k = kt * 32 + 4 * gg + (e & 3) + ((e >> 2) << 4);
            hp[e] = (_Float16)W2[k * HID + n];
        }
        *reinterpret_cast<half8*>(&sW2F[s * 8]) = hp;
    }
    if (tid < HID) { sB2[tid] = b2[tid]; sWoS[tid] = Wo[tid]; }
    for (int i = tid; i < HID * 3; i += 256) sWc[i] = Wc[i];
    __syncthreads();

    const int w = tid >> 6, lane = tid & 63, nl = lane & 15;
    const int ray = blockIdx.x * 4 + w;
    if (ray >= nRays) return;

    // ---- per-ray setup -----------------------------------------------------
    const float ox = raysOrg[ray * 3 + 0], oy = raysOrg[ray * 3 + 1], oz = raysOrg[ray * 3 + 2];
    const float dx = raysDir[ray * 3 + 0], dy = raysDir[ray * 3 + 1], dz = raysDir[ray * 3 + 2];
    const float nrm = sqrtf(dx * dx + dy * dy + dz * dz);
    const float rdx = dx / nrm, rdy = dy / nrm, rdz = dz / nrm;
    const float bo0 = bo[0];
    const float ST = 1.0f / 127.0f;

    float* su = sU[w];
    float* sv = sV[w];
    float* sred = sRed[w];
    for (int k = lane; k < HID; k += 64) {
        const float w1x = W1[k], w1y = W1[HID + k], w1z = W1[2 * HID + k];
        su[k] = ox * w1x + oy * w1y + oz * w1z + b1[k];
        sv[k] = rdx * w1x + rdy * w1y + rdz * w1z;
    }

    // ---- marching: chunk A (samples 0..63) ---------------------------------
#pragma unroll 1
    for (int mq = 0; mq < 4; ++mq)
        eval_q<false>(su, sv, sW2F, sB2, sWoS, nullptr, sred,
                      mq, NEARF + (float)(mq * 16 + nl) * ST, lane);
    asm volatile("s_waitcnt lgkmcnt(0)" ::: "memory");
    const float fA = sigmoidf_(sred[lane] + bo0) - 0.5f;

    const float f0 = __shfl(fA, 0);
    const float fAn = __shfl_down(fA, 1);
    const bool crossA = (lane < 63) && (fA * fAn < 0.f);
    const unsigned long long balA = __ballot(crossA);

    int idx = 0; float f_lo = 0.f, f_hi = 0.f; bool haschange = false;
    if (balA) {
        const int l = __ffsll(balA) - 1;
        idx = l; f_lo = __shfl(fA, l); f_hi = __shfl(fA, l + 1); haschange = true;
    } else if (f0 < 0.f) {
        // ---- chunk B (samples 64..127) -------------------------------------
        const float b0 = NEARF + 64.0f * ST;
#pragma unroll 1
        for (int mq = 0; mq < 4; ++mq)
            eval_q<false>(su, sv, sW2F, sB2, sWoS, nullptr, sred,
                          mq, b0 + (float)(mq * 16 + nl) * ST, lane);
        asm volatile("s_waitcnt lgkmcnt(0)" ::: "memory");
        const float fB = sigmoidf_(sred[lane] + bo0) - 0.5f;
        float fprev = __shfl_up(fB, 1);
        const float fA63 = __shfl(fA, 63);
        if (lane == 0) fprev = fA63;
        const bool crossB = (fprev * fB < 0.f);   // pair s = 63 + lane
        const unsigned long long balB = __ballot(crossB);
        if (balB) {
            const int l = __ffsll(balB) - 1;
            idx = 63 + l; f_lo = __shfl(fprev, l); f_hi = __shfl(fB, l); haschange = true;
        }
    }

    // ---- secant (uniform-d MFMA quarter evals, fp16 W2 path) ---------------
    float d_i;
    bool objmask = false;
    if (f0 >= 0.f) {
        d_i = 0.f;
    } else if (haschange && (f_lo < 0.f)) {
        float dlo = NEARF + (float)idx * ST;
        float dhi = NEARF + (float)(idx + 1) * ST;
        float flo = f_lo, fhi = f_hi;
#pragma unroll 1
        for (int itn = 0; itn < 8; ++itn) {
            float den = fhi - flo;
            if (fabsf(den) < 1e-12f) den = 1e-12f;
            const float dmid = dlo - flo * (dhi - dlo) / den;
            eval_q<false>(su, sv, sW2F, sB2, sWoS, nullptr, sred, 0, dmid, lane);
            asm volatile("s_waitcnt lgkmcnt(0)" ::: "memory");
            const float fmid = sigmoidf_(sred[nl] + bo0) - 0.5f;
            if (fmid < 0.f) { dlo = dmid; flo = fmid; }
            else            { dhi = dmid; fhi = fmid; }
        }
        float den = fhi - flo;
        if (fabsf(den) < 1e-12f) den = 1e-12f;
        d_i = dlo - flo * (dhi - dlo) / den;
        objmask = true;
    } else {
        d_i = __builtin_inff();
    }

    // ---- render: 64 samples, lane = sample ---------------------------------
    const int it = itp[0];
    const float delta = fmaxf(0.1f * expf(-2e-5f * (float)it), 0.01f);
    const float dsafe = objmask ? d_i : 1.0f;
    const float dnp = fmaxf(dsafe - delta, NEARF);
    const float dfp = fminf(dsafe + delta, FARF);
    const float t = (float)lane * (1.0f / 63.0f);
    const float depth = objmask ? (dnp * (1.f - t) + dfp * t)
                                : (NEARF * (1.f - t) + FARF * t);

#pragma unroll 1
    for (int mq = 0; mq < 4; ++mq) {
        const float dR = __shfl(depth, mq * 16 + nl);
        eval_q<true>(su, sv, sW2F, sB2, sWoS, sWc, sred, mq, dR, lane);
    }
    asm volatile("s_waitcnt lgkmcnt(0)" ::: "memory");
    const float lg = sred[lane];
    const float alpha = sigmoidf_(lg + bo0);
    float rc[3];
#pragma unroll
    for (int c = 0; c < 3; ++c) {
        const float x = sred[64 + 64 * c + lane]
            + rdx * Wc[128 * 3 + c] + rdy * Wc[129 * 3 + c] + rdz * Wc[130 * 3 + c]
            + bc[c];
        rc[c] = sigmoidf_(x);
    }

    // transmittance: exclusive prefix product of (1 - alpha + 1e-6)
    const float om = 1.f - alpha + 1e-6f;
    float incl = om;
#pragma unroll
    for (int off = 1; off < 64; off <<= 1) {
        const float p = __shfl_up(incl, off);
        if (lane >= off) incl *= p;
    }
    float trans = __shfl_up(incl, 1);
    if (lane == 0) trans = 1.f;
    const float wgt = alpha * trans;

    float s0 = wgt * rc[0], s1 = wgt * rc[1], s2 = wgt * rc[2], sd = wgt * depth;
#pragma unroll
    for (int off = 32; off; off >>= 1) {
        s0 += __shfl_xor(s0, off);
        s1 += __shfl_xor(s1, off);
        s2 += __shfl_xor(s2, off);
        sd += __shfl_xor(sd, off);
    }
    if (lane == 0) {
        outRGB[ray * 3 + 0] = s0;
        outRGB[ray * 3 + 1] = s1;
        outRGB[ray * 3 + 2] = s2;
        outD[ray] = sd;
        outM[ray] = objmask ? 1.f : 0.f;
    }
}

extern "C" void kernel_launch(void* const* d_in, const int* in_sizes, int n_in,
                              void* d_out, int out_size, void* d_ws, size_t ws_size,
                              hipStream_t stream) {
    (void)n_in; (void)out_size; (void)d_ws; (void)ws_size;
    const int R = in_sizes[0] / 3;
    float* out = reinterpret_cast<float*>(d_out);
    dim3 grid((R + 3) / 4), block(256);
    hipLaunchKernelGGL(unisurf_mfma_kernel, grid, block, 0, stream,
        (const float*)d_in[0], (const float*)d_in[1], (const float*)d_in[2],
        (const float*)d_in[3], (const float*)d_in[4], (const float*)d_in[5],
        (const float*)d_in[6], (const float*)d_in[7], (const float*)d_in[8],
        (const float*)d_in[9], (const int*)d_in[10],
        out, out + 3 * (size_t)R, out + 4 * (size_t)R, R);
}

// Round 13
// 235.112 us; speedup vs baseline: 1.2129x; 1.2129x over previous
//
#include <hip/hip_runtime.h>
#include <math.h>

// UNISURF renderer, MI355X — single-kernel MFMA, parallel-refine edition.
// R11 -> R12: (a) drop amdgpu_num_vgpr(168): R11 proved occupancy steps only
// at VGPR=64/128/256 (168 stayed at 2 waves/SIMD and lost scheduling
// freedom); back to natural ~188. (b) Replace the 8 SERIAL secant iterations
// (each a full eval_q + LDS round-trip, ~16K latency cycles on hit rays)
// with ONE parallel eval64 refine: 64 interior points of the bracket, ballot
// for first sign change (sub-bracket width 1.2e-4), then the final secant
// formula. Converges to the same root; removes the dominant serial block.
//
// Verified fragment layout (R5-R11 passed):
//   A: row = lane&15,  k = 4*(lane>>4) + (e&3) + 16*(e>>2)   (e = 0..7)
//   B: col = lane&15,  same k-map
//   C: col = lane&15,  row = 4*(lane>>4) + reg

#define HID 128
#define NEARF 0.8f
#define FARF  1.8f

typedef __attribute__((ext_vector_type(8))) _Float16 half8;
typedef __attribute__((ext_vector_type(4))) float f32x4;

__device__ __forceinline__ float sigmoidf_(float x) { return 1.0f / (1.0f + expf(-x)); }

// One M-quarter (16 sample-rows) of the 128->128->heads MLP on MFMA.
// dq = depth for this lane's A-row (sample row = lane&15 of quarter mq).
// Scatters per-sample results into sred[mq*16 + row] (+64/128/192 if RGB).
template<bool RGB>
__device__ __forceinline__ void eval_q(
    const float* __restrict__ su, const float* __restrict__ sv,
    const _Float16* __restrict__ sW2F,
    const float* __restrict__ sB2, const float* __restrict__ sWo,
    const float* __restrict__ sWc, float* __restrict__ sred,
    int mq, float dq, int lane)
{
    const int g = lane >> 4, nl = lane & 15;
    f32x4 acc[8];
#pragma unroll
    for (int nt = 0; nt < 8; ++nt) acc[nt] = (f32x4){0.f, 0.f, 0.f, 0.f};

#pragma unroll
    for (int kt = 0; kt < 4; ++kt) {
        const float* uk = su + kt * 32 + 4 * g;
        const float* vk = sv + kt * 32 + 4 * g;
        const float4 u0 = *reinterpret_cast<const float4*>(uk);
        const float4 u1 = *reinterpret_cast<const float4*>(uk + 16);
        const float4 v0 = *reinterpret_cast<const float4*>(vk);
        const float4 v1 = *reinterpret_cast<const float4*>(vk + 16);
        const float ue[8] = {u0.x, u0.y, u0.z, u0.w, u1.x, u1.y, u1.z, u1.w};
        const float ve[8] = {v0.x, v0.y, v0.z, v0.w, v1.x, v1.y, v1.z, v1.w};
        half8 Ah, Al;
#pragma unroll
        for (int e = 0; e < 8; ++e) {
            const float h = fmaxf(fmaf(dq, ve[e], ue[e]), 0.f);
            const _Float16 hh = (_Float16)h;
            Ah[e] = hh;
            Al[e] = (_Float16)(h - (float)hh);
        }
#pragma unroll
        for (int nt = 0; nt < 8; ++nt) {
            const int frag = (kt * 8 + nt) * 64 + lane;
            const half8 B = *reinterpret_cast<const half8*>(&sW2F[frag * 8]);
            acc[nt] = __builtin_amdgcn_mfma_f32_16x16x32_f16(Ah, B, acc[nt], 0, 0, 0);
            acc[nt] = __builtin_amdgcn_mfma_f32_16x16x32_f16(Al, B, acc[nt], 0, 0, 0);
        }
    }

    // epilogue: h2 = relu(acc + b2); head partials
    float pl[4], p0[4], p1[4], p2[4];
#pragma unroll
    for (int r = 0; r < 4; ++r) { pl[r] = 0.f; if (RGB) { p0[r] = 0.f; p1[r] = 0.f; p2[r] = 0.f; } }
#pragma unroll
    for (int nt = 0; nt < 8; ++nt) {
        const int j = nt * 16 + nl;
        const float b2l = sB2[j], wol = sWo[j];
        float wc0 = 0.f, wc1 = 0.f, wc2 = 0.f;
        if (RGB) { wc0 = sWc[j * 3 + 0]; wc1 = sWc[j * 3 + 1]; wc2 = sWc[j * 3 + 2]; }
#pragma unroll
        for (int r = 0; r < 4; ++r) {
            const float h2 = fmaxf(acc[nt][r] + b2l, 0.f);
            pl[r] = fmaf(h2, wol, pl[r]);
            if (RGB) {
                p0[r] = fmaf(h2, wc0, p0[r]);
                p1[r] = fmaf(h2, wc1, p1[r]);
                p2[r] = fmaf(h2, wc2, p2[r]);
            }
        }
    }
    // reduce across the 16 lanes of each g-group (j varies across them)
#pragma unroll
    for (int off = 1; off < 16; off <<= 1) {
#pragma unroll
        for (int r = 0; r < 4; ++r) {
            pl[r] += __shfl_xor(pl[r], off);
            if (RGB) {
                p0[r] += __shfl_xor(p0[r], off);
                p1[r] += __shfl_xor(p1[r], off);
                p2[r] += __shfl_xor(p2[r], off);
            }
        }
    }
    if (nl == 0) {
#pragma unroll
        for (int r = 0; r < 4; ++r) {
            const int m = mq * 16 + 4 * g + r;
            sred[m] = pl[r];
            if (RGB) { sred[64 + m] = p0[r]; sred[128 + m] = p1[r]; sred[192 + m] = p2[r]; }
        }
    }
}

extern "C" __global__ void __launch_bounds__(256, 1)
unisurf_mfma_kernel(
    const float* __restrict__ raysDir, const float* __restrict__ raysOrg,
    const float* __restrict__ W1, const float* __restrict__ b1,
    const float* __restrict__ W2, const float* __restrict__ b2,
    const float* __restrict__ Wo, const float* __restrict__ bo,
    const float* __restrict__ Wc, const float* __restrict__ bc,
    const int* __restrict__ itp,
    float* __restrict__ outRGB, float* __restrict__ outD, float* __restrict__ outM,
    int nRays)
{
    __shared__ __align__(16) _Float16 sW2F[2048 * 8];   // B-frag fp16 (32KB)
    __shared__ __align__(16) float sU[4][HID];
    __shared__ __align__(16) float sV[4][HID];
    __shared__ __align__(16) float sB2[HID];
    __shared__ __align__(16) float sWoS[HID];
    __shared__ __align__(16) float sWc[HID * 3];
    __shared__ __align__(16) float sRed[4][256];

    const int tid = threadIdx.x;
    // ---- stage W2 into MFMA B-fragment order, fp16 -------------------------
    for (int s = tid; s < 2048; s += 256) {
        const int ln = s & 63, ntg = (s >> 6) & 7, kt = s >> 9;
        const int n = ntg * 16 + (ln & 15), gg = ln >> 4;
        half8 hp;
#pragma unroll
        for (int e = 0; e < 8; ++e) {
            const int k = kt * 32 + 4 * gg + (e & 3) + ((e >> 2) << 4);
            hp[e] = (_Float16)W2[k * HID + n];
        }
        *reinterpret_cast<half8*>(&sW2F[s * 8]) = hp;
    }
    if (tid < HID) { sB2[tid] = b2[tid]; sWoS[tid] = Wo[tid]; }
    for (int i = tid; i < HID * 3; i += 256) sWc[i] = Wc[i];
    __syncthreads();

    const int w = tid >> 6, lane = tid & 63, nl = lane & 15;
    const int ray = blockIdx.x * 4 + w;
    if (ray >= nRays) return;

    // ---- per-ray setup -----------------------------------------------------
    const float ox = raysOrg[ray * 3 + 0], oy = raysOrg[ray * 3 + 1], oz = raysOrg[ray * 3 + 2];
    const float dx = raysDir[ray * 3 + 0], dy = raysDir[ray * 3 + 1], dz = raysDir[ray * 3 + 2];
    const float nrm = sqrtf(dx * dx + dy * dy + dz * dz);
    const float rdx = dx / nrm, rdy = dy / nrm, rdz = dz / nrm;
    const float bo0 = bo[0];
    const float ST = 1.0f / 127.0f;

    float* su = sU[w];
    float* sv = sV[w];
    float* sred = sRed[w];
    for (int k = lane; k < HID; k += 64) {
        const float w1x = W1[k], w1y = W1[HID + k], w1z = W1[2 * HID + k];
        su[k] = ox * w1x + oy * w1y + oz * w1z + b1[k];
        sv[k] = rdx * w1x + rdy * w1y + rdz * w1z;
    }

    // ---- marching: chunk A (samples 0..63) ---------------------------------
#pragma unroll 1
    for (int mq = 0; mq < 4; ++mq)
        eval_q<false>(su, sv, sW2F, sB2, sWoS, nullptr, sred,
                      mq, NEARF + (float)(mq * 16 + nl) * ST, lane);
    asm volatile("s_waitcnt lgkmcnt(0)" ::: "memory");
    const float fA = sigmoidf_(sred[lane] + bo0) - 0.5f;

    const float f0 = __shfl(fA, 0);
    const float fAn = __shfl_down(fA, 1);
    const bool crossA = (lane < 63) && (fA * fAn < 0.f);
    const unsigned long long balA = __ballot(crossA);

    int idx = 0; float f_lo = 0.f, f_hi = 0.f; bool haschange = false;
    if (balA) {
        const int l = __ffsll(balA) - 1;
        idx = l; f_lo = __shfl(fA, l); f_hi = __shfl(fA, l + 1); haschange = true;
    } else if (f0 < 0.f) {
        // ---- chunk B (samples 64..127) -------------------------------------
        const float b0 = NEARF + 64.0f * ST;
#pragma unroll 1
        for (int mq = 0; mq < 4; ++mq)
            eval_q<false>(su, sv, sW2F, sB2, sWoS, nullptr, sred,
                          mq, b0 + (float)(mq * 16 + nl) * ST, lane);
        asm volatile("s_waitcnt lgkmcnt(0)" ::: "memory");
        const float fB = sigmoidf_(sred[lane] + bo0) - 0.5f;
        float fprev = __shfl_up(fB, 1);
        const float fA63 = __shfl(fA, 63);
        if (lane == 0) fprev = fA63;
        const bool crossB = (fprev * fB < 0.f);   // pair s = 63 + lane
        const unsigned long long balB = __ballot(crossB);
        if (balB) {
            const int l = __ffsll(balB) - 1;
            idx = 63 + l; f_lo = __shfl(fprev, l); f_hi = __shfl(fB, l); haschange = true;
        }
    }

    // ---- refine: ONE parallel eval64 over the bracket + secant formula -----
    float d_i;
    bool objmask = false;
    if (f0 >= 0.f) {
        d_i = 0.f;
    } else if (haschange && (f_lo < 0.f)) {
        const float dlo = NEARF + (float)idx * ST;
        const float dhi = NEARF + (float)(idx + 1) * ST;
        const float h = (dhi - dlo) * (1.0f / 65.0f);
        // 64 interior points: lane L evaluates dlo + (L+1)*h
#pragma unroll 1
        for (int mq = 0; mq < 4; ++mq)
            eval_q<false>(su, sv, sW2F, sB2, sWoS, nullptr, sred,
                          mq, dlo + (float)(mq * 16 + nl + 1) * h, lane);
        asm volatile("s_waitcnt lgkmcnt(0)" ::: "memory");
        const float fR = sigmoidf_(sred[lane] + bo0) - 0.5f;
        const unsigned long long balR = __ballot(fR >= 0.f);
        float dl, fl, dh, fh;
        if (balR) {
            const int m = __ffsll(balR) - 1;      // first non-negative point
            dh = dlo + (float)(m + 1) * h; fh = __shfl(fR, m);
            if (m == 0) { dl = dlo; fl = f_lo; }
            else        { dl = dlo + (float)m * h; fl = __shfl(fR, m - 1); }
        } else {                                   // crossing in last sub-cell
            dl = dlo + 64.0f * h; fl = __shfl(fR, 63);
            dh = dhi;            fh = f_hi;
        }
        float den = fh - fl;
        if (fabsf(den) < 1e-12f) den = 1e-12f;
        d_i = dl - fl * (dh - dl) / den;
        objmask = true;
    } else {
        d_i = __builtin_inff();
    }

    // ---- render: 64 samples, lane = sample ---------------------------------
    const int it = itp[0];
    const float delta = fmaxf(0.1f * expf(-2e-5f * (float)it), 0.01f);
    const float dsafe = objmask ? d_i : 1.0f;
    const float dnp = fmaxf(dsafe - delta, NEARF);
    const float dfp = fminf(dsafe + delta, FARF);
    const float t = (float)lane * (1.0f / 63.0f);
    const float depth = objmask ? (dnp * (1.f - t) + dfp * t)
                                : (NEARF * (1.f - t) + FARF * t);

#pragma unroll 1
    for (int mq = 0; mq < 4; ++mq) {
        const float dR = __shfl(depth, mq * 16 + nl);
        eval_q<true>(su, sv, sW2F, sB2, sWoS, sWc, sred, mq, dR, lane);
    }
    asm volatile("s_waitcnt lgkmcnt(0)" ::: "memory");
    const float lg = sred[lane];
    const float alpha = sigmoidf_(lg + bo0);
    float rc[3];
#pragma unroll
    for (int c = 0; c < 3; ++c) {
        const float x = sred[64 + 64 * c + lane]
            + rdx * Wc[128 * 3 + c] + rdy * Wc[129 * 3 + c] + rdz * Wc[130 * 3 + c]
            + bc[c];
        rc[c] = sigmoidf_(x);
    }

    // transmittance: exclusive prefix product of (1 - alpha + 1e-6)
    const float om = 1.f - alpha + 1e-6f;
    float incl = om;
#pragma unroll
    for (int off = 1; off < 64; off <<= 1) {
        const float p = __shfl_up(incl, off);
        if (lane >= off) incl *= p;
    }
    float trans = __shfl_up(incl, 1);
    if (lane == 0) trans = 1.f;
    const float wgt = alpha * trans;

    float s0 = wgt * rc[0], s1 = wgt * rc[1], s2 = wgt * rc[2], sd = wgt * depth;
#pragma unroll
    for (int off = 32; off; off >>= 1) {
        s0 += __shfl_xor(s0, off);
        s1 += __shfl_xor(s1, off);
        s2 += __shfl_xor(s2, off);
        sd += __shfl_xor(sd, off);
    }
    if (lane == 0) {
        outRGB[ray * 3 + 0] = s0;
        outRGB[ray * 3 + 1] = s1;
        outRGB[ray * 3 + 2] = s2;
        outD[ray] = sd;
        outM[ray] = objmask ? 1.f : 0.f;
    }
}

extern "C" void kernel_launch(void* const* d_in, const int* in_sizes, int n_in,
                              void* d_out, int out_size, void* d_ws, size_t ws_size,
                              hipStream_t stream) {
    (void)n_in; (void)out_size; (void)d_ws; (void)ws_size;
    const int R = in_sizes[0] / 3;
    float* out = reinterpret_cast<float*>(d_out);
    dim3 grid((R + 3) / 4), block(256);
    hipLaunchKernelGGL(unisurf_mfma_kernel, grid, block, 0, stream,
        (const float*)d_in[0], (const float*)d_in[1], (const float*)d_in[2],
        (const float*)d_in[3], (const float*)d_in[4], (const float*)d_in[5],
        (const float*)d_in[6], (const float*)d_in[7], (const float*)d_in[8],
        (const float*)d_in[9], (const int*)d_in[10],
        out, out + 3 * (size_t)R, out + 4 * (size_t)R, R);
}

// Round 14
// 232.740 us; speedup vs baseline: 1.2253x; 1.0102x over previous
//
#include <hip/hip_runtime.h>
#include <math.h>

// UNISURF renderer, MI355X — single-kernel MFMA, paired-quarter ILP edition.
// R13 -> R14: eval_q (1 m-quarter, acc[8], 8 indep MFMA chains, 32 ds_reads
// per 64 MFMAs) -> eval_h (2 m-quarters, acc[2][8], 16 indep chains, SHARED
// B reads: 32 ds_reads per 128 MFMAs). Doubles in-wave ILP — the only lever
// left: VGPR=188 locks 2 waves/SIMD (occupancy steps only at 64/128/256,
// R11-proven) so TLP can't rise without the spill wall. Natural VGPR ~230
// expected; WRITE_SIZE is the spill sentinel.
//
// Verified fragment layout (R5-R13 passed):
//   A: row = lane&15,  k = 4*(lane>>4) + (e&3) + 16*(e>>2)   (e = 0..7)
//   B: col = lane&15,  same k-map
//   C: col = lane&15,  row = 4*(lane>>4) + reg

#define HID 128
#define NEARF 0.8f
#define FARF  1.8f

typedef __attribute__((ext_vector_type(8))) _Float16 half8;
typedef __attribute__((ext_vector_type(4))) float f32x4;

__device__ __forceinline__ float sigmoidf_(float x) { return 1.0f / (1.0f + expf(-x)); }

// Two M-quarters (quarters mq0, mq0+1 = 32 sample-rows) of the MLP on MFMA.
// dq0/dq1 = depth for this lane's A-row in each quarter (row = lane&15).
// B fragments are read once and feed both quarters' MFMAs.
// Scatters per-sample results into sred[(mq0+q)*16 + row] (+64/128/192 if RGB).
template<bool RGB>
__device__ __forceinline__ void eval_h(
    const float* __restrict__ su, const float* __restrict__ sv,
    const _Float16* __restrict__ sW2F,
    const float* __restrict__ sB2, const float* __restrict__ sWo,
    const float* __restrict__ sWc, float* __restrict__ sred,
    int mq0, float dq0, float dq1, int lane)
{
    const int g = lane >> 4, nl = lane & 15;
    f32x4 acc[2][8];
#pragma unroll
    for (int q = 0; q < 2; ++q)
#pragma unroll
        for (int nt = 0; nt < 8; ++nt) acc[q][nt] = (f32x4){0.f, 0.f, 0.f, 0.f};

#pragma unroll
    for (int kt = 0; kt < 4; ++kt) {
        const float* uk = su + kt * 32 + 4 * g;
        const float* vk = sv + kt * 32 + 4 * g;
        const float4 u0 = *reinterpret_cast<const float4*>(uk);
        const float4 u1 = *reinterpret_cast<const float4*>(uk + 16);
        const float4 v0 = *reinterpret_cast<const float4*>(vk);
        const float4 v1 = *reinterpret_cast<const float4*>(vk + 16);
        const float ue[8] = {u0.x, u0.y, u0.z, u0.w, u1.x, u1.y, u1.z, u1.w};
        const float ve[8] = {v0.x, v0.y, v0.z, v0.w, v1.x, v1.y, v1.z, v1.w};
        half8 Ah[2], Al[2];
#pragma unroll
        for (int q = 0; q < 2; ++q) {
            const float d = q ? dq1 : dq0;
#pragma unroll
            for (int e = 0; e < 8; ++e) {
                const float h = fmaxf(fmaf(d, ve[e], ue[e]), 0.f);
                const _Float16 hh = (_Float16)h;
                Ah[q][e] = hh;
                Al[q][e] = (_Float16)(h - (float)hh);
            }
        }
#pragma unroll
        for (int nt = 0; nt < 8; ++nt) {
            const int frag = (kt * 8 + nt) * 64 + lane;
            const half8 B = *reinterpret_cast<const half8*>(&sW2F[frag * 8]);  // shared
            acc[0][nt] = __builtin_amdgcn_mfma_f32_16x16x32_f16(Ah[0], B, acc[0][nt], 0, 0, 0);
            acc[0][nt] = __builtin_amdgcn_mfma_f32_16x16x32_f16(Al[0], B, acc[0][nt], 0, 0, 0);
            acc[1][nt] = __builtin_amdgcn_mfma_f32_16x16x32_f16(Ah[1], B, acc[1][nt], 0, 0, 0);
            acc[1][nt] = __builtin_amdgcn_mfma_f32_16x16x32_f16(Al[1], B, acc[1][nt], 0, 0, 0);
        }
    }

    // epilogue per quarter: h2 = relu(acc + b2); head partials; 16-lane reduce
#pragma unroll
    for (int q = 0; q < 2; ++q) {
        float pl[4], p0[4], p1[4], p2[4];
#pragma unroll
        for (int r = 0; r < 4; ++r) { pl[r] = 0.f; if (RGB) { p0[r] = 0.f; p1[r] = 0.f; p2[r] = 0.f; } }
#pragma unroll
        for (int nt = 0; nt < 8; ++nt) {
            const int j = nt * 16 + nl;
            const float b2l = sB2[j], wol = sWo[j];
            float wc0 = 0.f, wc1 = 0.f, wc2 = 0.f;
            if (RGB) { wc0 = sWc[j * 3 + 0]; wc1 = sWc[j * 3 + 1]; wc2 = sWc[j * 3 + 2]; }
#pragma unroll
            for (int r = 0; r < 4; ++r) {
                const float h2 = fmaxf(acc[q][nt][r] + b2l, 0.f);
                pl[r] = fmaf(h2, wol, pl[r]);
                if (RGB) {
                    p0[r] = fmaf(h2, wc0, p0[r]);
                    p1[r] = fmaf(h2, wc1, p1[r]);
                    p2[r] = fmaf(h2, wc2, p2[r]);
                }
            }
        }
#pragma unroll
        for (int off = 1; off < 16; off <<= 1) {
#pragma unroll
            for (int r = 0; r < 4; ++r) {
                pl[r] += __shfl_xor(pl[r], off);
                if (RGB) {
                    p0[r] += __shfl_xor(p0[r], off);
                    p1[r] += __shfl_xor(p1[r], off);
                    p2[r] += __shfl_xor(p2[r], off);
                }
            }
        }
        if (nl == 0) {
#pragma unroll
            for (int r = 0; r < 4; ++r) {
                const int m = (mq0 + q) * 16 + 4 * g + r;
                sred[m] = pl[r];
                if (RGB) { sred[64 + m] = p0[r]; sred[128 + m] = p1[r]; sred[192 + m] = p2[r]; }
            }
        }
    }
}

extern "C" __global__ void __launch_bounds__(256, 1)
unisurf_mfma_kernel(
    const float* __restrict__ raysDir, const float* __restrict__ raysOrg,
    const float* __restrict__ W1, const float* __restrict__ b1,
    const float* __restrict__ W2, const float* __restrict__ b2,
    const float* __restrict__ Wo, const float* __restrict__ bo,
    const float* __restrict__ Wc, const float* __restrict__ bc,
    const int* __restrict__ itp,
    float* __restrict__ outRGB, float* __restrict__ outD, float* __restrict__ outM,
    int nRays)
{
    __shared__ __align__(16) _Float16 sW2F[2048 * 8];   // B-frag fp16 (32KB)
    __shared__ __align__(16) float sU[4][HID];
    __shared__ __align__(16) float sV[4][HID];
    __shared__ __align__(16) float sB2[HID];
    __shared__ __align__(16) float sWoS[HID];
    __shared__ __align__(16) float sWc[HID * 3];
    __shared__ __align__(16) float sRed[4][256];

    const int tid = threadIdx.x;
    // ---- stage W2 into MFMA B-fragment order, fp16 -------------------------
    for (int s = tid; s < 2048; s += 256) {
        const int ln = s & 63, ntg = (s >> 6) & 7, kt = s >> 9;
        const int n = ntg * 16 + (ln & 15), gg = ln >> 4;
        half8 hp;
#pragma unroll
        for (int e = 0; e < 8; ++e) {
            const int k = kt * 32 + 4 * gg + (e & 3) + ((e >> 2) << 4);
            hp[e] = (_Float16)W2[k * HID + n];
        }
        *reinterpret_cast<half8*>(&sW2F[s * 8]) = hp;
    }
    if (tid < HID) { sB2[tid] = b2[tid]; sWoS[tid] = Wo[tid]; }
    for (int i = tid; i < HID * 3; i += 256) sWc[i] = Wc[i];
    __syncthreads();

    const int w = tid >> 6, lane = tid & 63, nl = lane & 15;
    const int ray = blockIdx.x * 4 + w;
    if (ray >= nRays) return;

    // ---- per-ray setup -----------------------------------------------------
    const float ox = raysOrg[ray * 3 + 0], oy = raysOrg[ray * 3 + 1], oz = raysOrg[ray * 3 + 2];
    const float dx = raysDir[ray * 3 + 0], dy = raysDir[ray * 3 + 1], dz = raysDir[ray * 3 + 2];
    const float nrm = sqrtf(dx * dx + dy * dy + dz * dz);
    const float rdx = dx / nrm, rdy = dy / nrm, rdz = dz / nrm;
    const float bo0 = bo[0];
    const float ST = 1.0f / 127.0f;

    float* su = sU[w];
    float* sv = sV[w];
    float* sred = sRed[w];
    for (int k = lane; k < HID; k += 64) {
        const float w1x = W1[k], w1y = W1[HID + k], w1z = W1[2 * HID + k];
        su[k] = ox * w1x + oy * w1y + oz * w1z + b1[k];
        sv[k] = rdx * w1x + rdy * w1y + rdz * w1z;
    }

    // ---- marching: chunk A (samples 0..63) ---------------------------------
#pragma unroll 1
    for (int mh = 0; mh < 2; ++mh)
        eval_h<false>(su, sv, sW2F, sB2, sWoS, nullptr, sred, mh * 2,
                      NEARF + (float)((mh * 2 + 0) * 16 + nl) * ST,
                      NEARF + (float)((mh * 2 + 1) * 16 + nl) * ST, lane);
    asm volatile("s_waitcnt lgkmcnt(0)" ::: "memory");
    const float fA = sigmoidf_(sred[lane] + bo0) - 0.5f;

    const float f0 = __shfl(fA, 0);
    const float fAn = __shfl_down(fA, 1);
    const bool crossA = (lane < 63) && (fA * fAn < 0.f);
    const unsigned long long balA = __ballot(crossA);

    int idx = 0; float f_lo = 0.f, f_hi = 0.f; bool haschange = false;
    if (balA) {
        const int l = __ffsll(balA) - 1;
        idx = l; f_lo = __shfl(fA, l); f_hi = __shfl(fA, l + 1); haschange = true;
    } else if (f0 < 0.f) {
        // ---- chunk B (samples 64..127) -------------------------------------
        const float b0 = NEARF + 64.0f * ST;
#pragma unroll 1
        for (int mh = 0; mh < 2; ++mh)
            eval_h<false>(su, sv, sW2F, sB2, sWoS, nullptr, sred, mh * 2,
                          b0 + (float)((mh * 2 + 0) * 16 + nl) * ST,
                          b0 + (float)((mh * 2 + 1) * 16 + nl) * ST, lane);
        asm volatile("s_waitcnt lgkmcnt(0)" ::: "memory");
        const float fB = sigmoidf_(sred[lane] + bo0) - 0.5f;
        float fprev = __shfl_up(fB, 1);
        const float fA63 = __shfl(fA, 63);
        if (lane == 0) fprev = fA63;
        const bool crossB = (fprev * fB < 0.f);   // pair s = 63 + lane
        const unsigned long long balB = __ballot(crossB);
        if (balB) {
            const int l = __ffsll(balB) - 1;
            idx = 63 + l; f_lo = __shfl(fprev, l); f_hi = __shfl(fB, l); haschange = true;
        }
    }

    // ---- refine: ONE parallel eval64 over the bracket + secant formula -----
    float d_i;
    bool objmask = false;
    if (f0 >= 0.f) {
        d_i = 0.f;
    } else if (haschange && (f_lo < 0.f)) {
        const float dlo = NEARF + (float)idx * ST;
        const float dhi = NEARF + (float)(idx + 1) * ST;
        const float h = (dhi - dlo) * (1.0f / 65.0f);
        // 64 interior points: lane L evaluates dlo + (L+1)*h
#pragma unroll 1
        for (int mh = 0; mh < 2; ++mh)
            eval_h<false>(su, sv, sW2F, sB2, sWoS, nullptr, sred, mh * 2,
                          dlo + (float)((mh * 2 + 0) * 16 + nl + 1) * h,
                          dlo + (float)((mh * 2 + 1) * 16 + nl + 1) * h, lane);
        asm volatile("s_waitcnt lgkmcnt(0)" ::: "memory");
        const float fR = sigmoidf_(sred[lane] + bo0) - 0.5f;
        const unsigned long long balR = __ballot(fR >= 0.f);
        float dl, fl, dh, fh;
        if (balR) {
            const int m = __ffsll(balR) - 1;      // first non-negative point
            dh = dlo + (float)(m + 1) * h; fh = __shfl(fR, m);
            if (m == 0) { dl = dlo; fl = f_lo; }
            else        { dl = dlo + (float)m * h; fl = __shfl(fR, m - 1); }
        } else {                                   // crossing in last sub-cell
            dl = dlo + 64.0f * h; fl = __shfl(fR, 63);
            dh = dhi;            fh = f_hi;
        }
        float den = fh - fl;
        if (fabsf(den) < 1e-12f) den = 1e-12f;
        d_i = dl - fl * (dh - dl) / den;
        objmask = true;
    } else {
        d_i = __builtin_inff();
    }

    // ---- render: 64 samples, lane = sample ---------------------------------
    const int it = itp[0];
    const float delta = fmaxf(0.1f * expf(-2e-5f * (float)it), 0.01f);
    const float dsafe = objmask ? d_i : 1.0f;
    const float dnp = fmaxf(dsafe - delta, NEARF);
    const float dfp = fminf(dsafe + delta, FARF);
    const float t = (float)lane * (1.0f / 63.0f);
    const float depth = objmask ? (dnp * (1.f - t) + dfp * t)
                                : (NEARF * (1.f - t) + FARF * t);

#pragma unroll 1
    for (int mh = 0; mh < 2; ++mh) {
        const float dR0 = __shfl(depth, (mh * 2 + 0) * 16 + nl);
        const float dR1 = __shfl(depth, (mh * 2 + 1) * 16 + nl);
        eval_h<true>(su, sv, sW2F, sB2, sWoS, sWc, sred, mh * 2, dR0, dR1, lane);
    }
    asm volatile("s_waitcnt lgkmcnt(0)" ::: "memory");
    const float lg = sred[lane];
    const float alpha = sigmoidf_(lg + bo0);
    float rc[3];
#pragma unroll
    for (int c = 0; c < 3; ++c) {
        const float x = sred[64 + 64 * c + lane]
            + rdx * Wc[128 * 3 + c] + rdy * Wc[129 * 3 + c] + rdz * Wc[130 * 3 + c]
            + bc[c];
        rc[c] = sigmoidf_(x);
    }

    // transmittance: exclusive prefix product of (1 - alpha + 1e-6)
    const float om = 1.f - alpha + 1e-6f;
    float incl = om;
#pragma unroll
    for (int off = 1; off < 64; off <<= 1) {
        const float p = __shfl_up(incl, off);
        if (lane >= off) incl *= p;
    }
    float trans = __shfl_up(incl, 1);
    if (lane == 0) trans = 1.f;
    const float wgt = alpha * trans;

    float s0 = wgt * rc[0], s1 = wgt * rc[1], s2 = wgt * rc[2], sd = wgt * depth;
#pragma unroll
    for (int off = 32; off; off >>= 1) {
        s0 += __shfl_xor(s0, off);
        s1 += __shfl_xor(s1, off);
        s2 += __shfl_xor(s2, off);
        sd += __shfl_xor(sd, off);
    }
    if (lane == 0) {
        outRGB[ray * 3 + 0] = s0;
        outRGB[ray * 3 + 1] = s1;
        outRGB[ray * 3 + 2] = s2;
        outD[ray] = sd;
        outM[ray] = objmask ? 1.f : 0.f;
    }
}

extern "C" void kernel_launch(void* const* d_in, const int* in_sizes, int n_in,
                              void* d_out, int out_size, void* d_ws, size_t ws_size,
                              hipStream_t stream) {
    (void)n_in; (void)out_size; (void)d_ws; (void)ws_size;
    const int R = in_sizes[0] / 3;
    float* out = reinterpret_cast<float*>(d_out);
    dim3 grid((R + 3) / 4), block(256);
    hipLaunchKernelGGL(unisurf_mfma_kernel, grid, block, 0, stream,
        (const float*)d_in[0], (const float*)d_in[1], (const float*)d_in[2],
        (const float*)d_in[3], (const float*)d_in[4], (const float*)d_in[5],
        (const float*)d_in[6], (const float*)d_in[7], (const float*)d_in[8],
        (const float*)d_in[9], (const int*)d_in[10],
        out, out + 3 * (size_t)R, out + 4 * (size_t)R, R);
}

// Round 15
// 203.644 us; speedup vs baseline: 1.4003x; 1.1429x over previous
//
#include <hip/hip_runtime.h>
#include <math.h>

// UNISURF renderer, MI355X — single-fp16-A edition.
// R14 -> R15: R14 proved MFMA-chain ILP is NOT the bottleneck (doubling
// chains: 177 -> 177 µs). Counter ratio VALU:MFMA = 2:1 says the issue
// stream is A-build VALU + epilogue. Fix: drop the A hi/lo split (W2 is
// already single fp16; the split only gold-plated the A side): halves MFMA
// count AND halves A-build ops. Refine now ONE eval_h (32 interior points,
// sub-bracket 2.4e-4). Expected absmax ~1.2-2e-2 (was 7.8e-3, thr 3.3e-2).
//
// Verified fragment layout (R5-R14 passed):
//   A: row = lane&15,  k = 4*(lane>>4) + (e&3) + 16*(e>>2)   (e = 0..7)
//   B: col = lane&15,  same k-map
//   C: col = lane&15,  row = 4*(lane>>4) + reg

#define HID 128
#define NEARF 0.8f
#define FARF  1.8f

typedef __attribute__((ext_vector_type(8))) _Float16 half8;
typedef __attribute__((ext_vector_type(4))) float f32x4;

__device__ __forceinline__ float sigmoidf_(float x) { return 1.0f / (1.0f + expf(-x)); }

// Two M-quarters (mq0, mq0+1 = 32 sample-rows) of the MLP on MFMA.
// Single-pass fp16 A; B fragments read once, shared by both quarters.
template<bool RGB>
__device__ __forceinline__ void eval_h(
    const float* __restrict__ su, const float* __restrict__ sv,
    const _Float16* __restrict__ sW2F,
    const float* __restrict__ sB2, const float* __restrict__ sWo,
    const float* __restrict__ sWc, float* __restrict__ sred,
    int mq0, float dq0, float dq1, int lane)
{
    const int g = lane >> 4, nl = lane & 15;
    f32x4 acc[2][8];
#pragma unroll
    for (int q = 0; q < 2; ++q)
#pragma unroll
        for (int nt = 0; nt < 8; ++nt) acc[q][nt] = (f32x4){0.f, 0.f, 0.f, 0.f};

#pragma unroll
    for (int kt = 0; kt < 4; ++kt) {
        const float* uk = su + kt * 32 + 4 * g;
        const float* vk = sv + kt * 32 + 4 * g;
        const float4 u0 = *reinterpret_cast<const float4*>(uk);
        const float4 u1 = *reinterpret_cast<const float4*>(uk + 16);
        const float4 v0 = *reinterpret_cast<const float4*>(vk);
        const float4 v1 = *reinterpret_cast<const float4*>(vk + 16);
        const float ue[8] = {u0.x, u0.y, u0.z, u0.w, u1.x, u1.y, u1.z, u1.w};
        const float ve[8] = {v0.x, v0.y, v0.z, v0.w, v1.x, v1.y, v1.z, v1.w};
        half8 Ah[2];
#pragma unroll
        for (int q = 0; q < 2; ++q) {
            const float d = q ? dq1 : dq0;
#pragma unroll
            for (int e = 0; e < 8; ++e)
                Ah[q][e] = (_Float16)fmaxf(fmaf(d, ve[e], ue[e]), 0.f);
        }
#pragma unroll
        for (int nt = 0; nt < 8; ++nt) {
            const int frag = (kt * 8 + nt) * 64 + lane;
            const half8 B = *reinterpret_cast<const half8*>(&sW2F[frag * 8]);  // shared
            acc[0][nt] = __builtin_amdgcn_mfma_f32_16x16x32_f16(Ah[0], B, acc[0][nt], 0, 0, 0);
            acc[1][nt] = __builtin_amdgcn_mfma_f32_16x16x32_f16(Ah[1], B, acc[1][nt], 0, 0, 0);
        }
    }

    // epilogue per quarter: h2 = relu(acc + b2); head partials; 16-lane reduce
#pragma unroll
    for (int q = 0; q < 2; ++q) {
        float pl[4], p0[4], p1[4], p2[4];
#pragma unroll
        for (int r = 0; r < 4; ++r) { pl[r] = 0.f; if (RGB) { p0[r] = 0.f; p1[r] = 0.f; p2[r] = 0.f; } }
#pragma unroll
        for (int nt = 0; nt < 8; ++nt) {
            const int j = nt * 16 + nl;
            const float b2l = sB2[j], wol = sWo[j];
            float wc0 = 0.f, wc1 = 0.f, wc2 = 0.f;
            if (RGB) { wc0 = sWc[j * 3 + 0]; wc1 = sWc[j * 3 + 1]; wc2 = sWc[j * 3 + 2]; }
#pragma unroll
            for (int r = 0; r < 4; ++r) {
                const float h2 = fmaxf(acc[q][nt][r] + b2l, 0.f);
                pl[r] = fmaf(h2, wol, pl[r]);
                if (RGB) {
                    p0[r] = fmaf(h2, wc0, p0[r]);
                    p1[r] = fmaf(h2, wc1, p1[r]);
                    p2[r] = fmaf(h2, wc2, p2[r]);
                }
            }
        }
#pragma unroll
        for (int off = 1; off < 16; off <<= 1) {
#pragma unroll
            for (int r = 0; r < 4; ++r) {
                pl[r] += __shfl_xor(pl[r], off);
                if (RGB) {
                    p0[r] += __shfl_xor(p0[r], off);
                    p1[r] += __shfl_xor(p1[r], off);
                    p2[r] += __shfl_xor(p2[r], off);
                }
            }
        }
        if (nl == 0) {
#pragma unroll
            for (int r = 0; r < 4; ++r) {
                const int m = (mq0 + q) * 16 + 4 * g + r;
                sred[m] = pl[r];
                if (RGB) { sred[64 + m] = p0[r]; sred[128 + m] = p1[r]; sred[192 + m] = p2[r]; }
            }
        }
    }
}

extern "C" __global__ void __launch_bounds__(256, 1)
unisurf_mfma_kernel(
    const float* __restrict__ raysDir, const float* __restrict__ raysOrg,
    const float* __restrict__ W1, const float* __restrict__ b1,
    const float* __restrict__ W2, const float* __restrict__ b2,
    const float* __restrict__ Wo, const float* __restrict__ bo,
    const float* __restrict__ Wc, const float* __restrict__ bc,
    const int* __restrict__ itp,
    float* __restrict__ outRGB, float* __restrict__ outD, float* __restrict__ outM,
    int nRays)
{
    __shared__ __align__(16) _Float16 sW2F[2048 * 8];   // B-frag fp16 (32KB)
    __shared__ __align__(16) float sU[4][HID];
    __shared__ __align__(16) float sV[4][HID];
    __shared__ __align__(16) float sB2[HID];
    __shared__ __align__(16) float sWoS[HID];
    __shared__ __align__(16) float sWc[HID * 3];
    __shared__ __align__(16) float sRed[4][256];

    const int tid = threadIdx.x;
    // ---- stage W2 into MFMA B-fragment order, fp16 -------------------------
    for (int s = tid; s < 2048; s += 256) {
        const int ln = s & 63, ntg = (s >> 6) & 7, kt = s >> 9;
        const int n = ntg * 16 + (ln & 15), gg = ln >> 4;
        half8 hp;
#pragma unroll
        for (int e = 0; e < 8; ++e) {
            const int k = kt * 32 + 4 * gg + (e & 3) + ((e >> 2) << 4);
            hp[e] = (_Float16)W2[k * HID + n];
        }
        *reinterpret_cast<half8*>(&sW2F[s * 8]) = hp;
    }
    if (tid < HID) { sB2[tid] = b2[tid]; sWoS[tid] = Wo[tid]; }
    for (int i = tid; i < HID * 3; i += 256) sWc[i] = Wc[i];
    __syncthreads();

    const int w = tid >> 6, lane = tid & 63, nl = lane & 15;
    const int ray = blockIdx.x * 4 + w;
    if (ray >= nRays) return;

    // ---- per-ray setup -----------------------------------------------------
    const float ox = raysOrg[ray * 3 + 0], oy = raysOrg[ray * 3 + 1], oz = raysOrg[ray * 3 + 2];
    const float dx = raysDir[ray * 3 + 0], dy = raysDir[ray * 3 + 1], dz = raysDir[ray * 3 + 2];
    const float nrm = sqrtf(dx * dx + dy * dy + dz * dz);
    const float rdx = dx / nrm, rdy = dy / nrm, rdz = dz / nrm;
    const float bo0 = bo[0];
    const float ST = 1.0f / 127.0f;

    float* su = sU[w];
    float* sv = sV[w];
    float* sred = sRed[w];
    for (int k = lane; k < HID; k += 64) {
        const float w1x = W1[k], w1y = W1[HID + k], w1z = W1[2 * HID + k];
        su[k] = ox * w1x + oy * w1y + oz * w1z + b1[k];
        sv[k] = rdx * w1x + rdy * w1y + rdz * w1z;
    }

    // ---- marching: chunk A (samples 0..63) ---------------------------------
#pragma unroll 1
    for (int mh = 0; mh < 2; ++mh)
        eval_h<false>(su, sv, sW2F, sB2, sWoS, nullptr, sred, mh * 2,
                      NEARF + (float)((mh * 2 + 0) * 16 + nl) * ST,
                      NEARF + (float)((mh * 2 + 1) * 16 + nl) * ST, lane);
    asm volatile("s_waitcnt lgkmcnt(0)" ::: "memory");
    const float fA = sigmoidf_(sred[lane] + bo0) - 0.5f;

    const float f0 = __shfl(fA, 0);
    const float fAn = __shfl_down(fA, 1);
    const bool crossA = (lane < 63) && (fA * fAn < 0.f);
    const unsigned long long balA = __ballot(crossA);

    int idx = 0; float f_lo = 0.f, f_hi = 0.f; bool haschange = false;
    if (balA) {
        const int l = __ffsll(balA) - 1;
        idx = l; f_lo = __shfl(fA, l); f_hi = __shfl(fA, l + 1); haschange = true;
    } else if (f0 < 0.f) {
        // ---- chunk B (samples 64..127) -------------------------------------
        const float b0 = NEARF + 64.0f * ST;
#pragma unroll 1
        for (int mh = 0; mh < 2; ++mh)
            eval_h<false>(su, sv, sW2F, sB2, sWoS, nullptr, sred, mh * 2,
                          b0 + (float)((mh * 2 + 0) * 16 + nl) * ST,
                          b0 + (float)((mh * 2 + 1) * 16 + nl) * ST, lane);
        asm volatile("s_waitcnt lgkmcnt(0)" ::: "memory");
        const float fB = sigmoidf_(sred[lane] + bo0) - 0.5f;
        float fprev = __shfl_up(fB, 1);
        const float fA63 = __shfl(fA, 63);
        if (lane == 0) fprev = fA63;
        const bool crossB = (fprev * fB < 0.f);   // pair s = 63 + lane
        const unsigned long long balB = __ballot(crossB);
        if (balB) {
            const int l = __ffsll(balB) - 1;
            idx = 63 + l; f_lo = __shfl(fprev, l); f_hi = __shfl(fB, l); haschange = true;
        }
    }

    // ---- refine: one eval_h (32 interior points) + secant formula ----------
    float d_i;
    bool objmask = false;
    if (f0 >= 0.f) {
        d_i = 0.f;
    } else if (haschange && (f_lo < 0.f)) {
        const float dlo = NEARF + (float)idx * ST;
        const float dhi = NEARF + (float)(idx + 1) * ST;
        const float h = (dhi - dlo) * (1.0f / 33.0f);
        // 32 interior points: lane L<32 evaluates dlo + (L+1)*h
        eval_h<false>(su, sv, sW2F, sB2, sWoS, nullptr, sred, 0,
                      dlo + (float)(nl + 1) * h,
                      dlo + (float)(16 + nl + 1) * h, lane);
        asm volatile("s_waitcnt lgkmcnt(0)" ::: "memory");
        const float fR = sigmoidf_(sred[lane & 31] + bo0) - 0.5f;
        const unsigned long long balR = __ballot((lane < 32) && (fR >= 0.f));
        float dl, fl, dh, fh;
        if (balR) {
            const int m = __ffsll(balR) - 1;      // first non-negative point
            dh = dlo + (float)(m + 1) * h; fh = __shfl(fR, m);
            if (m == 0) { dl = dlo; fl = f_lo; }
            else        { dl = dlo + (float)m * h; fl = __shfl(fR, m - 1); }
        } else {                                   // crossing in last sub-cell
            dl = dlo + 32.0f * h; fl = __shfl(fR, 31);
            dh = dhi;            fh = f_hi;
        }
        float den = fh - fl;
        if (fabsf(den) < 1e-12f) den = 1e-12f;
        d_i = dl - fl * (dh - dl) / den;
        objmask = true;
    } else {
        d_i = __builtin_inff();
    }

    // ---- render: 64 samples, lane = sample ---------------------------------
    const int it = itp[0];
    const float delta = fmaxf(0.1f * expf(-2e-5f * (float)it), 0.01f);
    const float dsafe = objmask ? d_i : 1.0f;
    const float dnp = fmaxf(dsafe - delta, NEARF);
    const float dfp = fminf(dsafe + delta, FARF);
    const float t = (float)lane * (1.0f / 63.0f);
    const float depth = objmask ? (dnp * (1.f - t) + dfp * t)
                                : (NEARF * (1.f - t) + FARF * t);

#pragma unroll 1
    for (int mh = 0; mh < 2; ++mh) {
        const float dR0 = __shfl(depth, (mh * 2 + 0) * 16 + nl);
        const float dR1 = __shfl(depth, (mh * 2 + 1) * 16 + nl);
        eval_h<true>(su, sv, sW2F, sB2, sWoS, sWc, sred, mh * 2, dR0, dR1, lane);
    }
    asm volatile("s_waitcnt lgkmcnt(0)" ::: "memory");
    const float lg = sred[lane];
    const float alpha = sigmoidf_(lg + bo0);
    float rc[3];
#pragma unroll
    for (int c = 0; c < 3; ++c) {
        const float x = sred[64 + 64 * c + lane]
            + rdx * Wc[128 * 3 + c] + rdy * Wc[129 * 3 + c] + rdz * Wc[130 * 3 + c]
            + bc[c];
        rc[c] = sigmoidf_(x);
    }

    // transmittance: exclusive prefix product of (1 - alpha + 1e-6)
    const float om = 1.f - alpha + 1e-6f;
    float incl = om;
#pragma unroll
    for (int off = 1; off < 64; off <<= 1) {
        const float p = __shfl_up(incl, off);
        if (lane >= off) incl *= p;
    }
    float trans = __shfl_up(incl, 1);
    if (lane == 0) trans = 1.f;
    const float wgt = alpha * trans;

    float s0 = wgt * rc[0], s1 = wgt * rc[1], s2 = wgt * rc[2], sd = wgt * depth;
#pragma unroll
    for (int off = 32; off; off >>= 1) {
        s0 += __shfl_xor(s0, off);
        s1 += __shfl_xor(s1, off);
        s2 += __shfl_xor(s2, off);
        sd += __shfl_xor(sd, off);
    }
    if (lane == 0) {
        outRGB[ray * 3 + 0] = s0;
        outRGB[ray * 3 + 1] = s1;
        outRGB[ray * 3 + 2] = s2;
        outD[ray] = sd;
        outM[ray] = objmask ? 1.f : 0.f;
    }
}

extern "C" void kernel_launch(void* const* d_in, const int* in_sizes, int n_in,
                              void* d_out, int out_size, void* d_ws, size_t ws_size,
                              hipStream_t stream) {
    (void)n_in; (void)out_size; (void)d_ws; (void)ws_size;
    const int R = in_sizes[0] / 3;
    float* out = reinterpret_cast<float*>(d_out);
    dim3 grid((R + 3) / 4), block(256);
    hipLaunchKernelGGL(unisurf_mfma_kernel, grid, block, 0, stream,
        (const float*)d_in[0], (const float*)d_in[1], (const float*)d_in[2],
        (const float*)d_in[3], (const float*)d_in[4], (const float*)d_in[5],
        (const float*)d_in[6], (const float*)d_in[7], (const float*)d_in[8],
        (const float*)d_in[9], (const int*)d_in[10],
        out, out + 3 * (size_t)R, out + 4 * (size_t)R, R);
}